// Round 10
// baseline (419.614 us; speedup 1.0000x reference)
//
#include <hip/hip_runtime.h>
#include <hip/hip_bf16.h>
#include <stdint.h>

typedef unsigned long long u64;
typedef unsigned int u32;
typedef __attribute__((ext_vector_type(8))) short bf16x8;
typedef __attribute__((ext_vector_type(4))) float f32x4;

__device__ __forceinline__ float ldv(const void* p, size_t idx, int mode) {
  return mode ? __bfloat162float(((const __hip_bfloat16*)p)[idx])
              : ((const float*)p)[idx];
}
__device__ __forceinline__ void stv(void* p, size_t idx, int mode, float v) {
  if (mode) ((__hip_bfloat16*)p)[idx] = __float2bfloat16(v);
  else      ((float*)p)[idx] = v;
}
__device__ __forceinline__ unsigned short f2bfb(float f) {  // RNE f32->bf16 bits
  u32 u = __float_as_uint(f);
  u32 r = u + 0x7fffu + ((u >> 16) & 1u);
  return (unsigned short)(r >> 16);
}
__device__ __forceinline__ u64 shfl64(u64 v, int src) {
  int lo = __shfl((int)(u32)(v & 0xffffffffu), src, 64);
  int hi = __shfl((int)(u32)(v >> 32), src, 64);
  return ((u64)(u32)hi << 32) | (u32)lo;
}
__device__ __forceinline__ u64 shflxor64(u64 v, int m) {
  int lo = __shfl_xor((int)(u32)(v & 0xffffffffu), m, 64);
  int hi = __shfl_xor((int)(u32)(v >> 32), m, 64);
  return ((u64)(u32)hi << 32) | (u32)lo;
}
__device__ __forceinline__ u64 shfl64w16(u64 v, int src) {  // width-16 shfl
  int lo = __shfl((int)(u32)(v & 0xffffffffu), src, 16);
  int hi = __shfl((int)(u32)(v >> 32), src, 16);
  return ((u64)(u32)hi << 32) | (u32)lo;
}

__global__ void PointNetSimple_61409442398998_kernel() {}

// ---------------------------------------------------------------------------
// setup: ONE kernel for dtype-detect + weight transpose/convert + vector cvt
// + prep (pos4/h0). Each block detects mode independently (32 u16 loads).
// ---------------------------------------------------------------------------
struct CvtEnt { const void* src; float* dst; int n; };
struct CvtArgs { CvtEnt e[12]; };
struct WEnt { const void* src; unsigned short* dst; int K, N, Kpad; };
struct WArgs { WEnt e[6]; };

__global__ void setup_kernel(const void* __restrict__ pos,
                             const void* __restrict__ nrm,
                             WArgs wa, CvtArgs ca,
                             int* __restrict__ flag,
                             float4* __restrict__ pos4,
                             float* __restrict__ h0, int n) {
  const unsigned short* u16p = (const unsigned short*)pos;
  int cnt = 0;
  for (int k = 0; k < 32; ++k) {
    int e = (u16p[k] >> 7) & 0xff;
    if (e >= 110 && e <= 140) cnt++;
  }
  const int mode = (cnt >= 26) ? 1 : 0;

  const int nprep = n >> 8;           // n/256 prep blocks
  const int b = blockIdx.x;
  if (b < nprep) {
    int i = b * 256 + threadIdx.x;
    float x = ldv(pos, 3*(size_t)i+0, mode);
    float y = ldv(pos, 3*(size_t)i+1, mode);
    float z = ldv(pos, 3*(size_t)i+2, mode);
    pos4[i] = make_float4(x, y, z, x*x + y*y + z*z);
    h0[6*(size_t)i+0] = x; h0[6*(size_t)i+1] = y; h0[6*(size_t)i+2] = z;
    h0[6*(size_t)i+3] = ldv(nrm, 3*(size_t)i+0, mode);
    h0[6*(size_t)i+4] = ldv(nrm, 3*(size_t)i+1, mode);
    h0[6*(size_t)i+5] = ldv(nrm, 3*(size_t)i+2, mode);
  } else {
    int r = b - nprep;   // 0..6
    if (r < 6) {
      WEnt ent = wa.e[r];
      for (int t = threadIdx.x; t < ent.N * ent.Kpad; t += blockDim.x) {
        int nn = t / ent.Kpad;
        int k  = t - nn * ent.Kpad;
        float v = (k < ent.K) ? ldv(ent.src, (size_t)k * ent.N + nn, mode) : 0.0f;
        ent.dst[t] = f2bfb(v);
      }
      if (r == 0 && threadIdx.x == 0) flag[0] = mode;
    } else {
      for (int t2 = 0; t2 < 12; ++t2) {
        CvtEnt ent = ca.e[t2];
        for (int t = threadIdx.x; t < ent.n; t += blockDim.x)
          ent.dst[t] = ldv(ent.src, t, mode);
      }
    }
  }
}

// ---------------------------------------------------------------------------
// knn v6: multi-target (4/wave) + COMBINED-OR EARLY-OUT.
// Hot path per 64-candidate group: 4 verbatim d2's, 4 compares, OR, ONE
// ballot + ONE branch. Slow path (~20% of groups, front-loaded) does
// per-target ballot/append/flush — machinery identical to v4/v5.
// d2 expression is the rounds-3..9 validated verbatim form (boundary-
// rounding sensitive — do not re-associate!).
// ---------------------------------------------------------------------------
#define KNN_TPB 512
#define KNN_WPB 8      // waves per block
#define KNN_TPW 4      // targets per wave
#define KCH 1024

__device__ __forceinline__ void knn_flush(u64* __restrict__ wbuf_t, int& cnt,
                                          u64& val, float& th, int lane) {
  u64 cand = (lane < cnt) ? wbuf_t[lane] : ~0ull;
  // bitonic sort ascending across 64 lanes
#pragma unroll
  for (int k = 2; k <= 64; k <<= 1) {
#pragma unroll
    for (int j = k >> 1; j > 0; j >>= 1) {
      u64 other = shflxor64(cand, j);
      bool up    = ((lane & k) == 0) || (k == 64);
      bool lower = ((lane & j) == 0);
      bool keepMin = (up == lower);
      u64 mn = cand < other ? cand : other;
      u64 mx = cand < other ? other : cand;
      cand = keepMin ? mn : mx;
    }
  }
  // merge: L[i] = min(val[i], cand[15-i]) is bitonic; 4-stage sort-16
  u64 rev = shfl64w16(cand, 15 - (lane & 15));
  u64 lo = val < rev ? val : rev;
#pragma unroll
  for (int j = 8; j > 0; j >>= 1) {
    u64 other = shflxor64(lo, j);
    bool lower = ((lane & j) == 0);
    u64 mn = lo < other ? lo : other;
    u64 mx = lo < other ? other : lo;
    lo = lower ? mn : mx;
  }
  val = (lane < 16) ? lo : ~0ull;
  u64 t15 = shfl64(val, 15);
  th = __uint_as_float((u32)(t15 >> 32));
  cnt = 0;
}

__global__ __launch_bounds__(KNN_TPB) void knn6_kernel(
    const float4* __restrict__ pos4, int* __restrict__ nbr, int n) {
  __shared__ float4 sp[2][KCH];
  __shared__ u64 buf[KNN_WPB][KNN_TPW][64];
  const int tid  = threadIdx.x;
  const int lane = tid & 63;
  const int wid  = tid >> 6;
  const int tbase = (blockIdx.x * KNN_WPB + wid) * KNN_TPW;

  float4 pi[KNN_TPW];
  float  thr[KNN_TPW];
  u64    val[KNN_TPW];
  int    cnt[KNN_TPW];
#pragma unroll
  for (int tt = 0; tt < KNN_TPW; ++tt) {
    pi[tt]  = pos4[tbase + tt];
    thr[tt] = 3.4e38f;
    val[tt] = ~0ull;
    cnt[tt] = 0;
  }

  for (int t = tid; t < KCH; t += KNN_TPB) sp[0][t] = pos4[t];
  __syncthreads();

  const int nch = n / KCH;
  for (int c = 0; c < nch; ++c) {
    const int cur = c & 1;
    float4 pre0, pre1;
    const bool more = (c + 1 < nch);
    if (more) {
      pre0 = pos4[(size_t)(c+1)*KCH + tid];
      pre1 = pos4[(size_t)(c+1)*KCH + KNN_TPB + tid];
    }
    for (int t = 0; t < KCH; t += 64) {
      float4 a = sp[cur][t + lane];
      float d2v[KNN_TPW];
      bool  pass[KNN_TPW];
#pragma unroll
      for (int tt = 0; tt < KNN_TPW; ++tt) {
        float d2 = (pi[tt].w + a.w)
                 - 2.0f*(pi[tt].x*a.x + pi[tt].y*a.y + pi[tt].z*a.z);
        d2 = fmaxf(d2, 0.0f);
        d2v[tt] = d2;
        pass[tt] = (d2 <= thr[tt]);
      }
      bool any = (pass[0] | pass[1]) | (pass[2] | pass[3]);
      if (__ballot(any) == 0ull) continue;           // hot-path early out

      const int base = c*KCH + t;
#pragma unroll
      for (int tt = 0; tt < KNN_TPW; ++tt) {
        u64 bal = __ballot(pass[tt]);
        if (bal) {
          int pc = __popcll(bal);
          if (cnt[tt] + pc > 64)
            knn_flush(&buf[wid][tt][0], cnt[tt], val[tt], thr[tt], lane);
          u32 mb = __builtin_amdgcn_mbcnt_lo((u32)bal, 0u);
          mb = __builtin_amdgcn_mbcnt_hi((u32)(bal >> 32), mb);
          if (pass[tt])
            buf[wid][tt][cnt[tt] + mb] =
                ((u64)__float_as_uint(d2v[tt]) << 32) | (u32)(base + lane);
          cnt[tt] += pc;
        }
      }
    }
    if (more) {
      sp[cur^1][tid] = pre0;
      sp[cur^1][KNN_TPB + tid] = pre1;
    }
    __syncthreads();
  }
#pragma unroll
  for (int tt = 0; tt < KNN_TPW; ++tt) {
    knn_flush(&buf[wid][tt][0], cnt[tt], val[tt], thr[tt], lane);
    if (lane < 16)
      nbr[(size_t)(tbase + tt)*16 + lane] = (int)(val[tt] & 0xffffffffu);
  }
}

// ---------------------------------------------------------------------------
// MFMA conv v2 (unchanged): one block = 8 nodes = 128 edge rows;
// zero __syncthreads; per-wave LDS bands only.
// ---------------------------------------------------------------------------
template<int CIN, int CMID, int KT1, int NT, int KT2>
__global__ __launch_bounds__(256) void conv_mfma2_kernel(
    const float* __restrict__ xin,
    const float4* __restrict__ pos4,
    const int* __restrict__ nbr,
    const int* __restrict__ flag,
    const unsigned short* __restrict__ WaT,   // [CMID][K1PAD] bf16
    const unsigned short* __restrict__ WbT,   // [CMID][CMID]  bf16
    const float* __restrict__ baf,
    const float* __restrict__ gmf,
    const float* __restrict__ btf,
    const float* __restrict__ bbf,
    float* __restrict__ xout,
    void* __restrict__ bout, size_t out_off)
{
  constexpr int K1PAD = KT1 * 32;
  constexpr int SB = CMID + 8;

  __shared__ unsigned short msgB[128 * SB];
  __shared__ float stage[4][32][20];

  const int tid  = threadIdx.x;
  const int lane = tid & 63;
  const int w    = tid >> 6;
  const int quad = lane >> 4;
  const int cl   = lane & 15;
  const int node0 = blockIdx.x * 8;
  const int mode = flag[0];

  bf16x8 afr[2][KT1];
#pragma unroll
  for (int mt = 0; mt < 2; ++mt) {
    const int node = node0 + w*2 + mt;
    const int j = nbr[(size_t)node*16 + cl];
    const float4 pin = pos4[node];
    const float4 pj = pos4[j];
    const float rx = pj.x - pin.x, ry = pj.y - pin.y, rz = pj.z - pin.z;
    if constexpr (CIN == 64) {
#pragma unroll
      for (int kt = 0; kt < 2; ++kt) {
        const float* p = &xin[(size_t)j*64 + kt*32 + quad*8];
        float4 a = *(const float4*)p;
        float4 b = *(const float4*)(p + 4);
        unsigned short o[8] = {f2bfb(a.x), f2bfb(a.y), f2bfb(a.z), f2bfb(a.w),
                               f2bfb(b.x), f2bfb(b.y), f2bfb(b.z), f2bfb(b.w)};
        afr[mt][kt] = *(bf16x8*)o;
      }
      unsigned short o[8] = {0,0,0,0,0,0,0,0};
      if (quad == 0) { o[0] = f2bfb(rx); o[1] = f2bfb(ry); o[2] = f2bfb(rz); }
      afr[mt][KT1-1] = *(bf16x8*)o;
    } else {  // CIN == 6, K = 9, KT1 = 1
      unsigned short o[8] = {0,0,0,0,0,0,0,0};
      if (quad == 0) {
        const float* p = &xin[(size_t)j*6];
        o[0] = f2bfb(p[0]); o[1] = f2bfb(p[1]); o[2] = f2bfb(p[2]);
        o[3] = f2bfb(p[3]); o[4] = f2bfb(p[4]); o[5] = f2bfb(p[5]);
        o[6] = f2bfb(rx);   o[7] = f2bfb(ry);
      } else if (quad == 1) {
        o[0] = f2bfb(rz);
      }
      afr[mt][0] = *(bf16x8*)o;
    }
  }

  f32x4 acc1[2][NT];
#pragma unroll
  for (int mt = 0; mt < 2; ++mt)
#pragma unroll
    for (int nt = 0; nt < NT; ++nt) acc1[mt][nt] = (f32x4){0.f, 0.f, 0.f, 0.f};
#pragma unroll
  for (int kt = 0; kt < KT1; ++kt)
#pragma unroll
    for (int nt = 0; nt < NT; ++nt) {
      bf16x8 bfr = *(const bf16x8*)&WaT[(size_t)(nt*16 + cl) * K1PAD + kt*32 + quad*8];
      acc1[0][nt] = __builtin_amdgcn_mfma_f32_16x16x32_bf16(afr[0][kt], bfr, acc1[0][nt], 0, 0, 0);
      acc1[1][nt] = __builtin_amdgcn_mfma_f32_16x16x32_bf16(afr[1][kt], bfr, acc1[1][nt], 0, 0, 0);
    }

#pragma unroll
  for (int nt = 0; nt < NT; ++nt) {
    float bac = baf[nt*16 + cl];
#pragma unroll
    for (int mt = 0; mt < 2; ++mt)
#pragma unroll
      for (int reg = 0; reg < 4; ++reg)
        stage[w][mt*16 + quad*4 + reg][cl] = acc1[mt][nt][reg] + bac;
    asm volatile("" ::: "memory");
    {
      int row = lane >> 1, gl = lane & 1;
      float4 va = *(const float4*)&stage[w][row][gl*8];
      float4 vb = *(const float4*)&stage[w][row][gl*8 + 4];
      float s  = va.x+va.y+va.z+va.w + vb.x+vb.y+vb.z+vb.w;
      float q  = va.x*va.x+va.y*va.y+va.z*va.z+va.w*va.w
               + vb.x*vb.x+vb.y*vb.y+vb.z*vb.z+vb.w*vb.w;
      float mu = s * 0.125f;
      float var = q * 0.125f - mu * mu;
      float inv = rsqrtf(fmaxf(var, 0.0f) + 1e-5f);
      int cb = nt*16 + gl*8;
      float vv[8] = {va.x, va.y, va.z, va.w, vb.x, vb.y, vb.z, vb.w};
      unsigned short o[8];
#pragma unroll
      for (int e = 0; e < 8; ++e) {
        float t = (vv[e] - mu) * inv * gmf[cb+e] + btf[cb+e];
        o[e] = f2bfb(fmaxf(t, 0.0f));
      }
      *(bf16x8*)&msgB[(w*32 + row) * SB + cb] = *(bf16x8*)o;
    }
    asm volatile("" ::: "memory");
  }

  f32x4 acc2[2][NT];
#pragma unroll
  for (int mt = 0; mt < 2; ++mt)
#pragma unroll
    for (int nt = 0; nt < NT; ++nt) acc2[mt][nt] = (f32x4){0.f, 0.f, 0.f, 0.f};
#pragma unroll
  for (int kt = 0; kt < KT2; ++kt) {
    bf16x8 af0 = *(const bf16x8*)&msgB[(w*32 + cl)      * SB + kt*32 + quad*8];
    bf16x8 af1 = *(const bf16x8*)&msgB[(w*32 + 16 + cl) * SB + kt*32 + quad*8];
#pragma unroll
    for (int nt = 0; nt < NT; ++nt) {
      bf16x8 bfr = *(const bf16x8*)&WbT[(size_t)(nt*16 + cl) * CMID + kt*32 + quad*8];
      acc2[0][nt] = __builtin_amdgcn_mfma_f32_16x16x32_bf16(af0, bfr, acc2[0][nt], 0, 0, 0);
      acc2[1][nt] = __builtin_amdgcn_mfma_f32_16x16x32_bf16(af1, bfr, acc2[1][nt], 0, 0, 0);
    }
  }

#pragma unroll
  for (int mt = 0; mt < 2; ++mt) {
    int node = node0 + w*2 + mt;
#pragma unroll
    for (int nt = 0; nt < NT; ++nt) {
      float m = fmaxf(fmaxf(acc2[mt][nt][0], acc2[mt][nt][1]),
                      fmaxf(acc2[mt][nt][2], acc2[mt][nt][3]));
      m = fmaxf(m, __shfl_xor(m, 16, 64));
      m = fmaxf(m, __shfl_xor(m, 32, 64));
      float v = fmaxf(m + bbf[nt*16 + cl], 0.0f);
      if (quad == 0) {
        size_t oi = (size_t)node * CMID + nt*16 + cl;
        if (xout) xout[oi] = v;
        stv(bout, out_off + oi, mode, v);
      }
    }
  }
}

// ---------------------------------------------------------------------------
extern "C" void kernel_launch(void* const* d_in, const int* in_sizes, int n_in,
                              void* d_out, int out_size, void* d_ws, size_t ws_size,
                              hipStream_t stream) {
  (void)n_in; (void)ws_size; (void)in_sizes;
  int n = out_size / 256;
  if (n <= 0 || (n & 255)) n = 16384;

  float* ws = (float*)d_ws;
  int*    flag = (int*)ws;
  float4* pos4 = (float4*)(ws + 16);
  float*  h0   = ws + 16 + (size_t)4*n;
  float*  h1   = ws + 16 + (size_t)10*n;
  float*  h2   = ws + 16 + (size_t)74*n;
  int*    nbr  = (int*)(ws + 16 + (size_t)138*n);
  float*  vbuf = ws + 16 + (size_t)154*n;
  unsigned short* wtbuf = (unsigned short*)(vbuf + 1024);

  const int vsz[12] = {64,64,64,64, 64,64,64,64, 128,128,128,128};
  const int vsrc[12] = {3,4,5,7, 9,10,11,13, 15,16,17,19};
  CvtArgs ca;
  float* vptr[12];
  {
    int off = 0;
    for (int t = 0; t < 12; ++t) {
      ca.e[t].src = d_in[vsrc[t]];
      ca.e[t].dst = vbuf + off;
      ca.e[t].n   = vsz[t];
      vptr[t] = vbuf + off;
      off += vsz[t];
    }
  }
  const int wK[6]    = {9, 64, 67, 64, 67, 128};
  const int wN[6]    = {64, 64, 64, 64, 128, 128};
  const int wKp[6]   = {32, 64, 96, 64, 96, 128};
  const int wsrc[6]  = {2, 6, 8, 12, 14, 18};
  WArgs wa;
  unsigned short* wptr[6];
  {
    int off = 0;
    for (int t = 0; t < 6; ++t) {
      wa.e[t].src  = d_in[wsrc[t]];
      wa.e[t].dst  = wtbuf + off;
      wa.e[t].K    = wK[t];
      wa.e[t].N    = wN[t];
      wa.e[t].Kpad = wKp[t];
      wptr[t] = wtbuf + off;
      off += wN[t] * wKp[t];
    }
  }

  setup_kernel<<<n/256 + 7, 256, 0, stream>>>(
      d_in[0], d_in[1], wa, ca, flag, pos4, h0, n);
  knn6_kernel<<<n/(KNN_WPB*KNN_TPW), KNN_TPB, 0, stream>>>(pos4, nbr, n);

  // <CIN, CMID, KT1, NT, KT2>
  conv_mfma2_kernel<6, 64, 1, 4, 2><<<n/8, 256, 0, stream>>>(
      h0, pos4, nbr, flag, wptr[0], wptr[1],
      vptr[0], vptr[1], vptr[2], vptr[3], h1, d_out, (size_t)0);
  conv_mfma2_kernel<64, 64, 3, 4, 2><<<n/8, 256, 0, stream>>>(
      h1, pos4, nbr, flag, wptr[2], wptr[3],
      vptr[4], vptr[5], vptr[6], vptr[7], h2, d_out, (size_t)n*64);
  conv_mfma2_kernel<64, 128, 3, 8, 4><<<n/8, 256, 0, stream>>>(
      h2, pos4, nbr, flag, wptr[4], wptr[5],
      vptr[8], vptr[9], vptr[10], vptr[11], (float*)nullptr, d_out, (size_t)n*128);
}

// Round 11
// 396.402 us; speedup vs baseline: 1.0586x; 1.0586x over previous
//
#include <hip/hip_runtime.h>
#include <hip/hip_bf16.h>
#include <stdint.h>

typedef unsigned long long u64;
typedef unsigned int u32;
typedef __attribute__((ext_vector_type(8))) short bf16x8;
typedef __attribute__((ext_vector_type(4))) float f32x4;

__device__ __forceinline__ float ldv(const void* p, size_t idx, int mode) {
  return mode ? __bfloat162float(((const __hip_bfloat16*)p)[idx])
              : ((const float*)p)[idx];
}
__device__ __forceinline__ void stv(void* p, size_t idx, int mode, float v) {
  if (mode) ((__hip_bfloat16*)p)[idx] = __float2bfloat16(v);
  else      ((float*)p)[idx] = v;
}
__device__ __forceinline__ unsigned short f2bfb(float f) {  // RNE f32->bf16 bits
  u32 u = __float_as_uint(f);
  u32 r = u + 0x7fffu + ((u >> 16) & 1u);
  return (unsigned short)(r >> 16);
}
__device__ __forceinline__ u64 shfl64(u64 v, int src) {
  int lo = __shfl((int)(u32)(v & 0xffffffffu), src, 64);
  int hi = __shfl((int)(u32)(v >> 32), src, 64);
  return ((u64)(u32)hi << 32) | (u32)lo;
}
__device__ __forceinline__ u64 shflxor64(u64 v, int m) {
  int lo = __shfl_xor((int)(u32)(v & 0xffffffffu), m, 64);
  int hi = __shfl_xor((int)(u32)(v >> 32), m, 64);
  return ((u64)(u32)hi << 32) | (u32)lo;
}
__device__ __forceinline__ u64 shfl64w16(u64 v, int src) {  // width-16 shfl
  int lo = __shfl((int)(u32)(v & 0xffffffffu), src, 16);
  int hi = __shfl((int)(u32)(v >> 32), src, 16);
  return ((u64)(u32)hi << 32) | (u32)lo;
}

__global__ void PointNetSimple_61409442398998_kernel() {}

// ---------------------------------------------------------------------------
// setup: ONE kernel for dtype-detect + weight transpose/convert + vector cvt
// + prep (pos4/h0). Each block detects mode independently (32 u16 loads).
// ---------------------------------------------------------------------------
struct CvtEnt { const void* src; float* dst; int n; };
struct CvtArgs { CvtEnt e[12]; };
struct WEnt { const void* src; unsigned short* dst; int K, N, Kpad; };
struct WArgs { WEnt e[6]; };

__global__ void setup_kernel(const void* __restrict__ pos,
                             const void* __restrict__ nrm,
                             WArgs wa, CvtArgs ca,
                             int* __restrict__ flag,
                             float4* __restrict__ pos4,
                             float* __restrict__ h0, int n) {
  const unsigned short* u16p = (const unsigned short*)pos;
  int cnt = 0;
  for (int k = 0; k < 32; ++k) {
    int e = (u16p[k] >> 7) & 0xff;
    if (e >= 110 && e <= 140) cnt++;
  }
  const int mode = (cnt >= 26) ? 1 : 0;

  const int nprep = n >> 8;           // n/256 prep blocks
  const int b = blockIdx.x;
  if (b < nprep) {
    int i = b * 256 + threadIdx.x;
    float x = ldv(pos, 3*(size_t)i+0, mode);
    float y = ldv(pos, 3*(size_t)i+1, mode);
    float z = ldv(pos, 3*(size_t)i+2, mode);
    pos4[i] = make_float4(x, y, z, x*x + y*y + z*z);
    h0[6*(size_t)i+0] = x; h0[6*(size_t)i+1] = y; h0[6*(size_t)i+2] = z;
    h0[6*(size_t)i+3] = ldv(nrm, 3*(size_t)i+0, mode);
    h0[6*(size_t)i+4] = ldv(nrm, 3*(size_t)i+1, mode);
    h0[6*(size_t)i+5] = ldv(nrm, 3*(size_t)i+2, mode);
  } else {
    int r = b - nprep;   // 0..6
    if (r < 6) {
      WEnt ent = wa.e[r];
      for (int t = threadIdx.x; t < ent.N * ent.Kpad; t += blockDim.x) {
        int nn = t / ent.Kpad;
        int k  = t - nn * ent.Kpad;
        float v = (k < ent.K) ? ldv(ent.src, (size_t)k * ent.N + nn, mode) : 0.0f;
        ent.dst[t] = f2bfb(v);
      }
      if (r == 0 && threadIdx.x == 0) flag[0] = mode;
    } else {
      for (int t2 = 0; t2 < 12; ++t2) {
        CvtEnt ent = ca.e[t2];
        for (int t = threadIdx.x; t < ent.n; t += blockDim.x)
          ent.dst[t] = ldv(ent.src, t, mode);
      }
    }
  }
}

// ---------------------------------------------------------------------------
// knn v7: 2 targets/wave (8192 waves -> 32/CU structural occupancy) +
// SAMPLING PRE-PASS (1024 strided candidates through normal machinery, then
// val/cnt reset, th KEPT -> main-scan pass rate ~1.6%) + combined-OR
// early-out (now effective). Flush th update is monotone (fminf) so the
// post-reset first flush cannot loosen th. Exactness: th is always a 16th-
// smallest of a subset => >= true 16th; every true-top-16 candidate passes;
// flush discards only non-top-16 of unions; main scan covers all N with no
// duplicates (val reset after sampling). Keys u64=(d2_bits<<32)|j = exact
// lax.top_k order. d2 expression VERBATIM (boundary-rounding frozen).
// ---------------------------------------------------------------------------
#define KNN_TPB 512
#define KNN_WPB 8      // waves per block
#define KNN_TPW 2      // targets per wave
#define KCH 1024

__device__ __forceinline__ void knn_flush(u64* __restrict__ wbuf_t, int& cnt,
                                          u64& val, float& th, int lane) {
  u64 cand = (lane < cnt) ? wbuf_t[lane] : ~0ull;
  // bitonic sort ascending across 64 lanes
#pragma unroll
  for (int k = 2; k <= 64; k <<= 1) {
#pragma unroll
    for (int j = k >> 1; j > 0; j >>= 1) {
      u64 other = shflxor64(cand, j);
      bool up    = ((lane & k) == 0) || (k == 64);
      bool lower = ((lane & j) == 0);
      bool keepMin = (up == lower);
      u64 mn = cand < other ? cand : other;
      u64 mx = cand < other ? other : cand;
      cand = keepMin ? mn : mx;
    }
  }
  // merge: L[i] = min(val[i], cand[15-i]) is bitonic; 4-stage sort-16
  u64 rev = shfl64w16(cand, 15 - (lane & 15));
  u64 lo = val < rev ? val : rev;
#pragma unroll
  for (int j = 8; j > 0; j >>= 1) {
    u64 other = shflxor64(lo, j);
    bool lower = ((lane & j) == 0);
    u64 mn = lo < other ? lo : other;
    u64 mx = lo < other ? other : lo;
    lo = lower ? mn : mx;
  }
  val = (lane < 16) ? lo : ~0ull;
  u64 t15 = shfl64(val, 15);
  th = fminf(th, __uint_as_float((u32)(t15 >> 32)));   // monotone tighten
  cnt = 0;
}

__global__ __launch_bounds__(KNN_TPB) void knn7_kernel(
    const float4* __restrict__ pos4, int* __restrict__ nbr, int n) {
  __shared__ float4 sp[2][KCH];                       // 32768 B
  __shared__ u64 buf[KNN_WPB][KNN_TPW][64];           //  8192 B
  const int tid  = threadIdx.x;
  const int lane = tid & 63;
  const int wid  = tid >> 6;
  const int tbase = (blockIdx.x * KNN_WPB + wid) * KNN_TPW;

  float4 pi[KNN_TPW];
  float  thr[KNN_TPW];
  u64    val[KNN_TPW];
  int    cnt[KNN_TPW];
#pragma unroll
  for (int tt = 0; tt < KNN_TPW; ++tt) {
    pi[tt]  = pos4[tbase + tt];
    thr[tt] = 3.4e38f;
    val[tt] = ~0ull;
    cnt[tt] = 0;
  }

  // ---- sampling pre-pass: 16 strided groups (identities later discarded) --
  {
    const int stride = n >> 4;
    for (int s = 0; s < 16; ++s) {
      float4 a = pos4[s*stride + lane];
      const int base = s*stride;
#pragma unroll
      for (int tt = 0; tt < KNN_TPW; ++tt) {
        float d2 = (pi[tt].w + a.w)
                 - 2.0f*(pi[tt].x*a.x + pi[tt].y*a.y + pi[tt].z*a.z);
        d2 = fmaxf(d2, 0.0f);
        bool pass = (d2 <= thr[tt]);
        u64 bal = __ballot(pass);
        if (bal) {
          int pc = __popcll(bal);
          if (cnt[tt] + pc > 64)
            knn_flush(&buf[wid][tt][0], cnt[tt], val[tt], thr[tt], lane);
          u32 mb = __builtin_amdgcn_mbcnt_lo((u32)bal, 0u);
          mb = __builtin_amdgcn_mbcnt_hi((u32)(bal >> 32), mb);
          if (pass)
            buf[wid][tt][cnt[tt] + mb] =
                ((u64)__float_as_uint(d2) << 32) | (u32)(base + lane);
          cnt[tt] += pc;
        }
      }
    }
    // one more flush so th reflects the full sample, then reset identities
#pragma unroll
    for (int tt = 0; tt < KNN_TPW; ++tt) {
      knn_flush(&buf[wid][tt][0], cnt[tt], val[tt], thr[tt], lane);
      val[tt] = ~0ull;
      cnt[tt] = 0;
    }
  }

  for (int t = tid; t < KCH; t += KNN_TPB) sp[0][t] = pos4[t];
  __syncthreads();

  const int nch = n / KCH;
  for (int c = 0; c < nch; ++c) {
    const int cur = c & 1;
    float4 pre0, pre1;
    const bool more = (c + 1 < nch);
    if (more) {
      pre0 = pos4[(size_t)(c+1)*KCH + tid];
      pre1 = pos4[(size_t)(c+1)*KCH + KNN_TPB + tid];
    }
#pragma unroll 2
    for (int t = 0; t < KCH; t += 64) {
      float4 a = sp[cur][t + lane];
      float d2v[KNN_TPW];
      bool  pass[KNN_TPW];
#pragma unroll
      for (int tt = 0; tt < KNN_TPW; ++tt) {
        float d2 = (pi[tt].w + a.w)
                 - 2.0f*(pi[tt].x*a.x + pi[tt].y*a.y + pi[tt].z*a.z);
        d2 = fmaxf(d2, 0.0f);
        d2v[tt] = d2;
        pass[tt] = (d2 <= thr[tt]);
      }
      bool any = pass[0] | pass[1];
      if (__ballot(any) != 0ull) {                    // rare after sampling
        const int base = c*KCH + t;
#pragma unroll
        for (int tt = 0; tt < KNN_TPW; ++tt) {
          u64 bal = __ballot(pass[tt]);
          if (bal) {
            int pc = __popcll(bal);
            if (cnt[tt] + pc > 64)
              knn_flush(&buf[wid][tt][0], cnt[tt], val[tt], thr[tt], lane);
            u32 mb = __builtin_amdgcn_mbcnt_lo((u32)bal, 0u);
            mb = __builtin_amdgcn_mbcnt_hi((u32)(bal >> 32), mb);
            if (pass[tt])
              buf[wid][tt][cnt[tt] + mb] =
                  ((u64)__float_as_uint(d2v[tt]) << 32) | (u32)(base + lane);
            cnt[tt] += pc;
          }
        }
      }
    }
    if (more) {
      sp[cur^1][tid] = pre0;
      sp[cur^1][KNN_TPB + tid] = pre1;
    }
    __syncthreads();
  }
#pragma unroll
  for (int tt = 0; tt < KNN_TPW; ++tt) {
    knn_flush(&buf[wid][tt][0], cnt[tt], val[tt], thr[tt], lane);
    if (lane < 16)
      nbr[(size_t)(tbase + tt)*16 + lane] = (int)(val[tt] & 0xffffffffu);
  }
}

// ---------------------------------------------------------------------------
// MFMA conv v2 (unchanged): one block = 8 nodes = 128 edge rows;
// zero __syncthreads; per-wave LDS bands only.
// ---------------------------------------------------------------------------
template<int CIN, int CMID, int KT1, int NT, int KT2>
__global__ __launch_bounds__(256) void conv_mfma2_kernel(
    const float* __restrict__ xin,
    const float4* __restrict__ pos4,
    const int* __restrict__ nbr,
    const int* __restrict__ flag,
    const unsigned short* __restrict__ WaT,   // [CMID][K1PAD] bf16
    const unsigned short* __restrict__ WbT,   // [CMID][CMID]  bf16
    const float* __restrict__ baf,
    const float* __restrict__ gmf,
    const float* __restrict__ btf,
    const float* __restrict__ bbf,
    float* __restrict__ xout,
    void* __restrict__ bout, size_t out_off)
{
  constexpr int K1PAD = KT1 * 32;
  constexpr int SB = CMID + 8;

  __shared__ unsigned short msgB[128 * SB];
  __shared__ float stage[4][32][20];

  const int tid  = threadIdx.x;
  const int lane = tid & 63;
  const int w    = tid >> 6;
  const int quad = lane >> 4;
  const int cl   = lane & 15;
  const int node0 = blockIdx.x * 8;
  const int mode = flag[0];

  bf16x8 afr[2][KT1];
#pragma unroll
  for (int mt = 0; mt < 2; ++mt) {
    const int node = node0 + w*2 + mt;
    const int j = nbr[(size_t)node*16 + cl];
    const float4 pin = pos4[node];
    const float4 pj = pos4[j];
    const float rx = pj.x - pin.x, ry = pj.y - pin.y, rz = pj.z - pin.z;
    if constexpr (CIN == 64) {
#pragma unroll
      for (int kt = 0; kt < 2; ++kt) {
        const float* p = &xin[(size_t)j*64 + kt*32 + quad*8];
        float4 a = *(const float4*)p;
        float4 b = *(const float4*)(p + 4);
        unsigned short o[8] = {f2bfb(a.x), f2bfb(a.y), f2bfb(a.z), f2bfb(a.w),
                               f2bfb(b.x), f2bfb(b.y), f2bfb(b.z), f2bfb(b.w)};
        afr[mt][kt] = *(bf16x8*)o;
      }
      unsigned short o[8] = {0,0,0,0,0,0,0,0};
      if (quad == 0) { o[0] = f2bfb(rx); o[1] = f2bfb(ry); o[2] = f2bfb(rz); }
      afr[mt][KT1-1] = *(bf16x8*)o;
    } else {  // CIN == 6, K = 9, KT1 = 1
      unsigned short o[8] = {0,0,0,0,0,0,0,0};
      if (quad == 0) {
        const float* p = &xin[(size_t)j*6];
        o[0] = f2bfb(p[0]); o[1] = f2bfb(p[1]); o[2] = f2bfb(p[2]);
        o[3] = f2bfb(p[3]); o[4] = f2bfb(p[4]); o[5] = f2bfb(p[5]);
        o[6] = f2bfb(rx);   o[7] = f2bfb(ry);
      } else if (quad == 1) {
        o[0] = f2bfb(rz);
      }
      afr[mt][0] = *(bf16x8*)o;
    }
  }

  f32x4 acc1[2][NT];
#pragma unroll
  for (int mt = 0; mt < 2; ++mt)
#pragma unroll
    for (int nt = 0; nt < NT; ++nt) acc1[mt][nt] = (f32x4){0.f, 0.f, 0.f, 0.f};
#pragma unroll
  for (int kt = 0; kt < KT1; ++kt)
#pragma unroll
    for (int nt = 0; nt < NT; ++nt) {
      bf16x8 bfr = *(const bf16x8*)&WaT[(size_t)(nt*16 + cl) * K1PAD + kt*32 + quad*8];
      acc1[0][nt] = __builtin_amdgcn_mfma_f32_16x16x32_bf16(afr[0][kt], bfr, acc1[0][nt], 0, 0, 0);
      acc1[1][nt] = __builtin_amdgcn_mfma_f32_16x16x32_bf16(afr[1][kt], bfr, acc1[1][nt], 0, 0, 0);
    }

#pragma unroll
  for (int nt = 0; nt < NT; ++nt) {
    float bac = baf[nt*16 + cl];
#pragma unroll
    for (int mt = 0; mt < 2; ++mt)
#pragma unroll
      for (int reg = 0; reg < 4; ++reg)
        stage[w][mt*16 + quad*4 + reg][cl] = acc1[mt][nt][reg] + bac;
    asm volatile("" ::: "memory");
    {
      int row = lane >> 1, gl = lane & 1;
      float4 va = *(const float4*)&stage[w][row][gl*8];
      float4 vb = *(const float4*)&stage[w][row][gl*8 + 4];
      float s  = va.x+va.y+va.z+va.w + vb.x+vb.y+vb.z+vb.w;
      float q  = va.x*va.x+va.y*va.y+va.z*va.z+va.w*va.w
               + vb.x*vb.x+vb.y*vb.y+vb.z*vb.z+vb.w*vb.w;
      float mu = s * 0.125f;
      float var = q * 0.125f - mu * mu;
      float inv = rsqrtf(fmaxf(var, 0.0f) + 1e-5f);
      int cb = nt*16 + gl*8;
      float vv[8] = {va.x, va.y, va.z, va.w, vb.x, vb.y, vb.z, vb.w};
      unsigned short o[8];
#pragma unroll
      for (int e = 0; e < 8; ++e) {
        float t = (vv[e] - mu) * inv * gmf[cb+e] + btf[cb+e];
        o[e] = f2bfb(fmaxf(t, 0.0f));
      }
      *(bf16x8*)&msgB[(w*32 + row) * SB + cb] = *(bf16x8*)o;
    }
    asm volatile("" ::: "memory");
  }

  f32x4 acc2[2][NT];
#pragma unroll
  for (int mt = 0; mt < 2; ++mt)
#pragma unroll
    for (int nt = 0; nt < NT; ++nt) acc2[mt][nt] = (f32x4){0.f, 0.f, 0.f, 0.f};
#pragma unroll
  for (int kt = 0; kt < KT2; ++kt) {
    bf16x8 af0 = *(const bf16x8*)&msgB[(w*32 + cl)      * SB + kt*32 + quad*8];
    bf16x8 af1 = *(const bf16x8*)&msgB[(w*32 + 16 + cl) * SB + kt*32 + quad*8];
#pragma unroll
    for (int nt = 0; nt < NT; ++nt) {
      bf16x8 bfr = *(const bf16x8*)&WbT[(size_t)(nt*16 + cl) * CMID + kt*32 + quad*8];
      acc2[0][nt] = __builtin_amdgcn_mfma_f32_16x16x32_bf16(af0, bfr, acc2[0][nt], 0, 0, 0);
      acc2[1][nt] = __builtin_amdgcn_mfma_f32_16x16x32_bf16(af1, bfr, acc2[1][nt], 0, 0, 0);
    }
  }

#pragma unroll
  for (int mt = 0; mt < 2; ++mt) {
    int node = node0 + w*2 + mt;
#pragma unroll
    for (int nt = 0; nt < NT; ++nt) {
      float m = fmaxf(fmaxf(acc2[mt][nt][0], acc2[mt][nt][1]),
                      fmaxf(acc2[mt][nt][2], acc2[mt][nt][3]));
      m = fmaxf(m, __shfl_xor(m, 16, 64));
      m = fmaxf(m, __shfl_xor(m, 32, 64));
      float v = fmaxf(m + bbf[nt*16 + cl], 0.0f);
      if (quad == 0) {
        size_t oi = (size_t)node * CMID + nt*16 + cl;
        if (xout) xout[oi] = v;
        stv(bout, out_off + oi, mode, v);
      }
    }
  }
}

// ---------------------------------------------------------------------------
extern "C" void kernel_launch(void* const* d_in, const int* in_sizes, int n_in,
                              void* d_out, int out_size, void* d_ws, size_t ws_size,
                              hipStream_t stream) {
  (void)n_in; (void)ws_size; (void)in_sizes;
  int n = out_size / 256;
  if (n <= 0 || (n & 255)) n = 16384;

  float* ws = (float*)d_ws;
  int*    flag = (int*)ws;
  float4* pos4 = (float4*)(ws + 16);
  float*  h0   = ws + 16 + (size_t)4*n;
  float*  h1   = ws + 16 + (size_t)10*n;
  float*  h2   = ws + 16 + (size_t)74*n;
  int*    nbr  = (int*)(ws + 16 + (size_t)138*n);
  float*  vbuf = ws + 16 + (size_t)154*n;
  unsigned short* wtbuf = (unsigned short*)(vbuf + 1024);

  const int vsz[12] = {64,64,64,64, 64,64,64,64, 128,128,128,128};
  const int vsrc[12] = {3,4,5,7, 9,10,11,13, 15,16,17,19};
  CvtArgs ca;
  float* vptr[12];
  {
    int off = 0;
    for (int t = 0; t < 12; ++t) {
      ca.e[t].src = d_in[vsrc[t]];
      ca.e[t].dst = vbuf + off;
      ca.e[t].n   = vsz[t];
      vptr[t] = vbuf + off;
      off += vsz[t];
    }
  }
  const int wK[6]    = {9, 64, 67, 64, 67, 128};
  const int wN[6]    = {64, 64, 64, 64, 128, 128};
  const int wKp[6]   = {32, 64, 96, 64, 96, 128};
  const int wsrc[6]  = {2, 6, 8, 12, 14, 18};
  WArgs wa;
  unsigned short* wptr[6];
  {
    int off = 0;
    for (int t = 0; t < 6; ++t) {
      wa.e[t].src  = d_in[wsrc[t]];
      wa.e[t].dst  = wtbuf + off;
      wa.e[t].K    = wK[t];
      wa.e[t].N    = wN[t];
      wa.e[t].Kpad = wKp[t];
      wptr[t] = wtbuf + off;
      off += wN[t] * wKp[t];
    }
  }

  setup_kernel<<<n/256 + 7, 256, 0, stream>>>(
      d_in[0], d_in[1], wa, ca, flag, pos4, h0, n);
  knn7_kernel<<<n/(KNN_WPB*KNN_TPW), KNN_TPB, 0, stream>>>(pos4, nbr, n);

  // <CIN, CMID, KT1, NT, KT2>
  conv_mfma2_kernel<6, 64, 1, 4, 2><<<n/8, 256, 0, stream>>>(
      h0, pos4, nbr, flag, wptr[0], wptr[1],
      vptr[0], vptr[1], vptr[2], vptr[3], h1, d_out, (size_t)0);
  conv_mfma2_kernel<64, 64, 3, 4, 2><<<n/8, 256, 0, stream>>>(
      h1, pos4, nbr, flag, wptr[2], wptr[3],
      vptr[4], vptr[5], vptr[6], vptr[7], h2, d_out, (size_t)n*64);
  conv_mfma2_kernel<64, 128, 3, 8, 4><<<n/8, 256, 0, stream>>>(
      h2, pos4, nbr, flag, wptr[4], wptr[5],
      vptr[8], vptr[9], vptr[10], vptr[11], (float*)nullptr, d_out, (size_t)n*128);
}

// Round 12
// 373.843 us; speedup vs baseline: 1.1224x; 1.0603x over previous
//
#include <hip/hip_runtime.h>
#include <hip/hip_bf16.h>
#include <stdint.h>

typedef unsigned long long u64;
typedef unsigned int u32;
typedef __attribute__((ext_vector_type(8))) short bf16x8;
typedef __attribute__((ext_vector_type(8))) unsigned short u16x8;
typedef __attribute__((ext_vector_type(4))) float f32x4;

__device__ __forceinline__ float ldv(const void* p, size_t idx, int mode) {
  return mode ? __bfloat162float(((const __hip_bfloat16*)p)[idx])
              : ((const float*)p)[idx];
}
__device__ __forceinline__ void stv(void* p, size_t idx, int mode, float v) {
  if (mode) ((__hip_bfloat16*)p)[idx] = __float2bfloat16(v);
  else      ((float*)p)[idx] = v;
}
__device__ __forceinline__ unsigned short f2bfb(float f) {  // RNE f32->bf16 bits
  u32 u = __float_as_uint(f);
  u32 r = u + 0x7fffu + ((u >> 16) & 1u);
  return (unsigned short)(r >> 16);
}
__device__ __forceinline__ float bfb2f(unsigned short b) {
  return __uint_as_float((u32)b << 16);
}
__device__ __forceinline__ u64 shfl64(u64 v, int src) {
  int lo = __shfl((int)(u32)(v & 0xffffffffu), src, 64);
  int hi = __shfl((int)(u32)(v >> 32), src, 64);
  return ((u64)(u32)hi << 32) | (u32)lo;
}
__device__ __forceinline__ u64 shflxor64(u64 v, int m) {
  int lo = __shfl_xor((int)(u32)(v & 0xffffffffu), m, 64);
  int hi = __shfl_xor((int)(u32)(v >> 32), m, 64);
  return ((u64)(u32)hi << 32) | (u32)lo;
}
__device__ __forceinline__ u64 shfl64w16(u64 v, int src) {  // width-16 shfl
  int lo = __shfl((int)(u32)(v & 0xffffffffu), src, 16);
  int hi = __shfl((int)(u32)(v >> 32), src, 16);
  return ((u64)(u32)hi << 32) | (u32)lo;
}

__global__ void PointNetSimple_61409442398998_kernel() {}

// ---------------------------------------------------------------------------
// setup: ONE kernel for dtype-detect + weight transpose/convert + vector cvt
// + prep (pos4/h0). Each block detects mode independently (32 u16 loads).
// ---------------------------------------------------------------------------
struct CvtEnt { const void* src; float* dst; int n; };
struct CvtArgs { CvtEnt e[12]; };
struct WEnt { const void* src; unsigned short* dst; int K, N, Kpad; };
struct WArgs { WEnt e[6]; };

__global__ void setup_kernel(const void* __restrict__ pos,
                             const void* __restrict__ nrm,
                             WArgs wa, CvtArgs ca,
                             int* __restrict__ flag,
                             float4* __restrict__ pos4,
                             float* __restrict__ h0, int n) {
  const unsigned short* u16p = (const unsigned short*)pos;
  int cnt = 0;
  for (int k = 0; k < 32; ++k) {
    int e = (u16p[k] >> 7) & 0xff;
    if (e >= 110 && e <= 140) cnt++;
  }
  const int mode = (cnt >= 26) ? 1 : 0;

  const int nprep = n >> 8;           // n/256 prep blocks
  const int b = blockIdx.x;
  if (b < nprep) {
    int i = b * 256 + threadIdx.x;
    float x = ldv(pos, 3*(size_t)i+0, mode);
    float y = ldv(pos, 3*(size_t)i+1, mode);
    float z = ldv(pos, 3*(size_t)i+2, mode);
    pos4[i] = make_float4(x, y, z, x*x + y*y + z*z);
    h0[6*(size_t)i+0] = x; h0[6*(size_t)i+1] = y; h0[6*(size_t)i+2] = z;
    h0[6*(size_t)i+3] = ldv(nrm, 3*(size_t)i+0, mode);
    h0[6*(size_t)i+4] = ldv(nrm, 3*(size_t)i+1, mode);
    h0[6*(size_t)i+5] = ldv(nrm, 3*(size_t)i+2, mode);
  } else {
    int r = b - nprep;   // 0..6
    if (r < 6) {
      WEnt ent = wa.e[r];
      for (int t = threadIdx.x; t < ent.N * ent.Kpad; t += blockDim.x) {
        int nn = t / ent.Kpad;
        int k  = t - nn * ent.Kpad;
        float v = (k < ent.K) ? ldv(ent.src, (size_t)k * ent.N + nn, mode) : 0.0f;
        ent.dst[t] = f2bfb(v);
      }
      if (r == 0 && threadIdx.x == 0) flag[0] = mode;
    } else {
      for (int t2 = 0; t2 < 12; ++t2) {
        CvtEnt ent = ca.e[t2];
        for (int t = threadIdx.x; t < ent.n; t += blockDim.x)
          ent.dst[t] = ldv(ent.src, t, mode);
      }
    }
  }
}

// ---------------------------------------------------------------------------
// knn v4 (RESTORED verbatim from round 7 — proven 171.5 us): wave-per-target,
// compaction via mbcnt append + exact bitonic flush. Keys u64 =
// (d2_bits<<32)|j -> exact lax.top_k order incl. index tie-break.
// d2 expression verbatim (boundary-rounding frozen).
// ---------------------------------------------------------------------------
#define KNN_TPB 512
#define KNN_WPB 8
#define KCH 1024

__device__ __forceinline__ void knn_flush(u64* __restrict__ wbuf, int& cnt,
                                          u64& val, u64& t15, float& th,
                                          int lane) {
  u64 cand = (lane < cnt) ? wbuf[lane] : ~0ull;
  // bitonic sort ascending across 64 lanes
#pragma unroll
  for (int k = 2; k <= 64; k <<= 1) {
#pragma unroll
    for (int j = k >> 1; j > 0; j >>= 1) {
      u64 other = shflxor64(cand, j);
      bool up    = ((lane & k) == 0) || (k == 64);
      bool lower = ((lane & j) == 0);
      bool keepMin = (up == lower);
      u64 mn = cand < other ? cand : other;
      u64 mx = cand < other ? other : cand;
      cand = keepMin ? mn : mx;
    }
  }
  // merge: L[i] = min(val[i], cand[15-i]) is bitonic; 4-stage sort-16
  u64 rev = shfl64w16(cand, 15 - (lane & 15));
  u64 lo = val < rev ? val : rev;
#pragma unroll
  for (int j = 8; j > 0; j >>= 1) {
    u64 other = shflxor64(lo, j);
    bool lower = ((lane & j) == 0);
    u64 mn = lo < other ? lo : other;
    u64 mx = lo < other ? other : lo;
    lo = lower ? mn : mx;
  }
  val = (lane < 16) ? lo : ~0ull;
  t15 = shfl64(val, 15);
  th = __uint_as_float((u32)(t15 >> 32));
  cnt = 0;
}

__global__ __launch_bounds__(KNN_TPB) void knn4_kernel(
    const float4* __restrict__ pos4, int* __restrict__ nbr, int n) {
  __shared__ float4 sp[2][KCH];
  __shared__ u64 buf[KNN_WPB][72];
  const int tid  = threadIdx.x;
  const int lane = tid & 63;
  const int wid  = tid >> 6;
  const int i    = blockIdx.x * KNN_WPB + wid;
  const float4 pi = pos4[i];
  u64* wbuf = &buf[wid][0];

  u64 val = ~0ull;
  u64 t15 = ~0ull;
  float th = 3.4e38f;
  int cnt = 0;

  for (int t = tid; t < KCH; t += KNN_TPB) sp[0][t] = pos4[t];
  __syncthreads();

  const int nch = n / KCH;
  for (int c = 0; c < nch; ++c) {
    const int cur = c & 1;
    float4 pre0, pre1;
    const bool more = (c + 1 < nch);
    if (more) {
      pre0 = pos4[(size_t)(c+1)*KCH + tid];
      pre1 = pos4[(size_t)(c+1)*KCH + KNN_TPB + tid];
    }
#pragma unroll 2
    for (int t = 0; t < KCH; t += 64) {
      float4 a = sp[cur][t + lane];
      float d2 = (pi.w + a.w) - 2.0f*(pi.x*a.x + pi.y*a.y + pi.z*a.z);
      d2 = fmaxf(d2, 0.0f);
      bool pass = (d2 <= th);
      u64 bal = __ballot(pass);
      if (bal) {
        int pc = __popcll(bal);
        if (cnt + pc > 64) knn_flush(wbuf, cnt, val, t15, th, lane);
        u32 mb = __builtin_amdgcn_mbcnt_lo((u32)bal, 0u);
        mb = __builtin_amdgcn_mbcnt_hi((u32)(bal >> 32), mb);
        if (pass)
          wbuf[cnt + mb] = ((u64)__float_as_uint(d2) << 32) | (u32)(c*KCH + t + lane);
        cnt += pc;
      }
    }
    if (more) {
      sp[cur^1][tid] = pre0;
      sp[cur^1][KNN_TPB + tid] = pre1;
    }
    __syncthreads();
  }
  knn_flush(wbuf, cnt, val, t15, th, lane);
  if (lane < 16) nbr[(size_t)i*16 + lane] = (int)(val & 0xffffffffu);
}

// ---------------------------------------------------------------------------
// MFMA conv v3: as round-6 v2 (zero __syncthreads, per-wave bands) but the
// GN stage is bf16 (u16[4][32][24] = 6 KB vs 10 KB fp32) -> conv3 LDS
// 40960 B = exactly 4 blocks/CU (was 3), conv1/2 -> 6 blocks/CU.
// __launch_bounds__(256,4) keeps VGPR <=128 so register pressure doesn't
// undercut the LDS-derived occupancy. Numerics: bf16 quantize before GN
// stats (est. +0.005 absmax, threshold 0.061).
// ---------------------------------------------------------------------------
template<int CIN, int CMID, int KT1, int NT, int KT2>
__global__ __launch_bounds__(256, 4) void conv_mfma3_kernel(
    const float* __restrict__ xin,
    const float4* __restrict__ pos4,
    const int* __restrict__ nbr,
    const int* __restrict__ flag,
    const unsigned short* __restrict__ WaT,   // [CMID][K1PAD] bf16
    const unsigned short* __restrict__ WbT,   // [CMID][CMID]  bf16
    const float* __restrict__ baf,
    const float* __restrict__ gmf,
    const float* __restrict__ btf,
    const float* __restrict__ bbf,
    float* __restrict__ xout,
    void* __restrict__ bout, size_t out_off)
{
  constexpr int K1PAD = KT1 * 32;
  constexpr int SB = CMID + 8;

  __shared__ unsigned short msgB[128 * SB];
  __shared__ __align__(16) unsigned short stageb[4][32][24];

  const int tid  = threadIdx.x;
  const int lane = tid & 63;
  const int w    = tid >> 6;
  const int quad = lane >> 4;
  const int cl   = lane & 15;
  const int node0 = blockIdx.x * 8;
  const int mode = flag[0];

  bf16x8 afr[2][KT1];
#pragma unroll
  for (int mt = 0; mt < 2; ++mt) {
    const int node = node0 + w*2 + mt;
    const int j = nbr[(size_t)node*16 + cl];
    const float4 pin = pos4[node];
    const float4 pj = pos4[j];
    const float rx = pj.x - pin.x, ry = pj.y - pin.y, rz = pj.z - pin.z;
    if constexpr (CIN == 64) {
#pragma unroll
      for (int kt = 0; kt < 2; ++kt) {
        const float* p = &xin[(size_t)j*64 + kt*32 + quad*8];
        float4 a = *(const float4*)p;
        float4 b = *(const float4*)(p + 4);
        unsigned short o[8] = {f2bfb(a.x), f2bfb(a.y), f2bfb(a.z), f2bfb(a.w),
                               f2bfb(b.x), f2bfb(b.y), f2bfb(b.z), f2bfb(b.w)};
        afr[mt][kt] = *(bf16x8*)o;
      }
      unsigned short o[8] = {0,0,0,0,0,0,0,0};
      if (quad == 0) { o[0] = f2bfb(rx); o[1] = f2bfb(ry); o[2] = f2bfb(rz); }
      afr[mt][KT1-1] = *(bf16x8*)o;
    } else {  // CIN == 6, K = 9, KT1 = 1
      unsigned short o[8] = {0,0,0,0,0,0,0,0};
      if (quad == 0) {
        const float* p = &xin[(size_t)j*6];
        o[0] = f2bfb(p[0]); o[1] = f2bfb(p[1]); o[2] = f2bfb(p[2]);
        o[3] = f2bfb(p[3]); o[4] = f2bfb(p[4]); o[5] = f2bfb(p[5]);
        o[6] = f2bfb(rx);   o[7] = f2bfb(ry);
      } else if (quad == 1) {
        o[0] = f2bfb(rz);
      }
      afr[mt][0] = *(bf16x8*)o;
    }
  }

  f32x4 acc1[2][NT];
#pragma unroll
  for (int mt = 0; mt < 2; ++mt)
#pragma unroll
    for (int nt = 0; nt < NT; ++nt) acc1[mt][nt] = (f32x4){0.f, 0.f, 0.f, 0.f};
#pragma unroll
  for (int kt = 0; kt < KT1; ++kt)
#pragma unroll
    for (int nt = 0; nt < NT; ++nt) {
      bf16x8 bfr = *(const bf16x8*)&WaT[(size_t)(nt*16 + cl) * K1PAD + kt*32 + quad*8];
      acc1[0][nt] = __builtin_amdgcn_mfma_f32_16x16x32_bf16(afr[0][kt], bfr, acc1[0][nt], 0, 0, 0);
      acc1[1][nt] = __builtin_amdgcn_mfma_f32_16x16x32_bf16(afr[1][kt], bfr, acc1[1][nt], 0, 0, 0);
    }

  // ---- +bias -> per-wave bf16 stage -> GroupNorm(8)+ReLU -> msgB ----
#pragma unroll
  for (int nt = 0; nt < NT; ++nt) {
    float bac = baf[nt*16 + cl];
#pragma unroll
    for (int mt = 0; mt < 2; ++mt)
#pragma unroll
      for (int reg = 0; reg < 4; ++reg)
        stageb[w][mt*16 + quad*4 + reg][cl] = f2bfb(acc1[mt][nt][reg] + bac);
    asm volatile("" ::: "memory");
    {
      int row = lane >> 1, gl = lane & 1;
      u16x8 hv = *(const u16x8*)&stageb[w][row][gl*8];
      float vv[8];
#pragma unroll
      for (int e = 0; e < 8; ++e) vv[e] = bfb2f(hv[e]);
      float s = 0.f, q = 0.f;
#pragma unroll
      for (int e = 0; e < 8; ++e) { s += vv[e]; q += vv[e]*vv[e]; }
      float mu = s * 0.125f;
      float var = q * 0.125f - mu * mu;
      float inv = rsqrtf(fmaxf(var, 0.0f) + 1e-5f);
      int cb = nt*16 + gl*8;
      unsigned short o[8];
#pragma unroll
      for (int e = 0; e < 8; ++e) {
        float t = (vv[e] - mu) * inv * gmf[cb+e] + btf[cb+e];
        o[e] = f2bfb(fmaxf(t, 0.0f));
      }
      *(bf16x8*)&msgB[(w*32 + row) * SB + cb] = *(bf16x8*)o;
    }
    asm volatile("" ::: "memory");
  }

  f32x4 acc2[2][NT];
#pragma unroll
  for (int mt = 0; mt < 2; ++mt)
#pragma unroll
    for (int nt = 0; nt < NT; ++nt) acc2[mt][nt] = (f32x4){0.f, 0.f, 0.f, 0.f};
#pragma unroll
  for (int kt = 0; kt < KT2; ++kt) {
    bf16x8 af0 = *(const bf16x8*)&msgB[(w*32 + cl)      * SB + kt*32 + quad*8];
    bf16x8 af1 = *(const bf16x8*)&msgB[(w*32 + 16 + cl) * SB + kt*32 + quad*8];
#pragma unroll
    for (int nt = 0; nt < NT; ++nt) {
      bf16x8 bfr = *(const bf16x8*)&WbT[(size_t)(nt*16 + cl) * CMID + kt*32 + quad*8];
      acc2[0][nt] = __builtin_amdgcn_mfma_f32_16x16x32_bf16(af0, bfr, acc2[0][nt], 0, 0, 0);
      acc2[1][nt] = __builtin_amdgcn_mfma_f32_16x16x32_bf16(af1, bfr, acc2[1][nt], 0, 0, 0);
    }
  }

#pragma unroll
  for (int mt = 0; mt < 2; ++mt) {
    int node = node0 + w*2 + mt;
#pragma unroll
    for (int nt = 0; nt < NT; ++nt) {
      float m = fmaxf(fmaxf(acc2[mt][nt][0], acc2[mt][nt][1]),
                      fmaxf(acc2[mt][nt][2], acc2[mt][nt][3]));
      m = fmaxf(m, __shfl_xor(m, 16, 64));
      m = fmaxf(m, __shfl_xor(m, 32, 64));
      float v = fmaxf(m + bbf[nt*16 + cl], 0.0f);
      if (quad == 0) {
        size_t oi = (size_t)node * CMID + nt*16 + cl;
        if (xout) xout[oi] = v;
        stv(bout, out_off + oi, mode, v);
      }
    }
  }
}

// ---------------------------------------------------------------------------
extern "C" void kernel_launch(void* const* d_in, const int* in_sizes, int n_in,
                              void* d_out, int out_size, void* d_ws, size_t ws_size,
                              hipStream_t stream) {
  (void)n_in; (void)ws_size; (void)in_sizes;
  int n = out_size / 256;
  if (n <= 0 || (n & 255)) n = 16384;

  float* ws = (float*)d_ws;
  int*    flag = (int*)ws;
  float4* pos4 = (float4*)(ws + 16);
  float*  h0   = ws + 16 + (size_t)4*n;
  float*  h1   = ws + 16 + (size_t)10*n;
  float*  h2   = ws + 16 + (size_t)74*n;
  int*    nbr  = (int*)(ws + 16 + (size_t)138*n);
  float*  vbuf = ws + 16 + (size_t)154*n;
  unsigned short* wtbuf = (unsigned short*)(vbuf + 1024);

  const int vsz[12] = {64,64,64,64, 64,64,64,64, 128,128,128,128};
  const int vsrc[12] = {3,4,5,7, 9,10,11,13, 15,16,17,19};
  CvtArgs ca;
  float* vptr[12];
  {
    int off = 0;
    for (int t = 0; t < 12; ++t) {
      ca.e[t].src = d_in[vsrc[t]];
      ca.e[t].dst = vbuf + off;
      ca.e[t].n   = vsz[t];
      vptr[t] = vbuf + off;
      off += vsz[t];
    }
  }
  const int wK[6]    = {9, 64, 67, 64, 67, 128};
  const int wN[6]    = {64, 64, 64, 64, 128, 128};
  const int wKp[6]   = {32, 64, 96, 64, 96, 128};
  const int wsrc[6]  = {2, 6, 8, 12, 14, 18};
  WArgs wa;
  unsigned short* wptr[6];
  {
    int off = 0;
    for (int t = 0; t < 6; ++t) {
      wa.e[t].src  = d_in[wsrc[t]];
      wa.e[t].dst  = wtbuf + off;
      wa.e[t].K    = wK[t];
      wa.e[t].N    = wN[t];
      wa.e[t].Kpad = wKp[t];
      wptr[t] = wtbuf + off;
      off += wN[t] * wKp[t];
    }
  }

  setup_kernel<<<n/256 + 7, 256, 0, stream>>>(
      d_in[0], d_in[1], wa, ca, flag, pos4, h0, n);
  knn4_kernel<<<n/KNN_WPB, KNN_TPB, 0, stream>>>(pos4, nbr, n);

  // <CIN, CMID, KT1, NT, KT2>
  conv_mfma3_kernel<6, 64, 1, 4, 2><<<n/8, 256, 0, stream>>>(
      h0, pos4, nbr, flag, wptr[0], wptr[1],
      vptr[0], vptr[1], vptr[2], vptr[3], h1, d_out, (size_t)0);
  conv_mfma3_kernel<64, 64, 3, 4, 2><<<n/8, 256, 0, stream>>>(
      h1, pos4, nbr, flag, wptr[2], wptr[3],
      vptr[4], vptr[5], vptr[6], vptr[7], h2, d_out, (size_t)n*64);
  conv_mfma3_kernel<64, 128, 3, 8, 4><<<n/8, 256, 0, stream>>>(
      h2, pos4, nbr, flag, wptr[4], wptr[5],
      vptr[8], vptr[9], vptr[10], vptr[11], (float*)nullptr, d_out, (size_t)n*128);
}